// Round 3
// baseline (129.569 us; speedup 1.0000x reference)
//
#include <hip/hip_runtime.h>

// Quantizer_189: 1-D VQ codebook lookup. x: [16,1,512,512] fp32 (N=4,194,304
// scalars; C=D=1 so transposes are no-ops), weight: [128,1].
//
// Reference model (NumPy fp32, per-op rounding, NO fma):
//   dist_k = fl( fl( fl(x*x) + fl(w_k*w_k) ) - fl( fl(2x) * w_k ) )
//   idx    = np.argmin(dist) — first minimum wins
//   out    = w[idx]
//
// CRITICAL: HIP __fmul_rn etc. are plain ops and device default is
// -ffp-contract=fast-honor-pragmas, which fused s - tx*w into fma in round 1
// and broke bit-exactness. Block contraction with pragma + opaque asm
// barriers on every product.

constexpr int K     = 128;
constexpr int EPT   = 8;
constexpr int BLOCK = 256;

__global__ __launch_bounds__(BLOCK) void vq_kernel(const float* __restrict__ x,
                                                   const float* __restrict__ w,
                                                   float* __restrict__ out,
                                                   long n, int kk) {
#pragma clang fp contract(off)
    // Stage (w, fl(w*w)) interleaved: one ds_read_b64 per k, wave-uniform
    // index -> broadcast, no bank conflicts. 1 KB.
    __shared__ float2 wp[K];
    for (int i = threadIdx.x; i < K; i += blockDim.x) {
        float v  = (i < kk) ? w[i] : __builtin_inff();
        float v2 = v * v;
        asm volatile("" : "+v"(v2));      // keep fl(w*w) a standalone product
        wp[i] = make_float2(v, v2);
    }
    __syncthreads();

    long base = ((long)blockIdx.x * BLOCK + threadIdx.x) * (long)EPT;
    if (base + EPT <= n) {
        float4 a = *(const float4*)(x + base);
        float4 b = *(const float4*)(x + base + 4);
        float xs[EPT] = {a.x, a.y, a.z, a.w, b.x, b.y, b.z, b.w};
        float x2[EPT], tx[EPT], best[EPT], bw[EPT];
#pragma unroll
        for (int e = 0; e < EPT; ++e) {
            float xv = xs[e];
            float xx = xv * xv;           // fl(x*x)
            asm volatile("" : "+v"(xx));  // block fma(xv,xv,w2) fusion
            x2[e]   = xx;
            tx[e]   = xv + xv;            // fl(2x) (exact)
            best[e] = __builtin_inff();
            bw[e]   = 0.0f;
        }
#pragma unroll 4
        for (int k = 0; k < K; ++k) {
            float2 p = wp[k];
#pragma unroll
            for (int e = 0; e < EPT; ++e) {
                float s    = x2[e] + p.y;     // fl(x^2 + w^2)
                float prod = tx[e] * p.x;     // fl(2x * w)
                asm volatile("" : "+v"(prod));// block fma(-tx,w,s) fusion
                float d = s - prod;           // fl(s - prod)
                bool lt = d < best[e];        // strict: first-min-wins
                best[e] = lt ? d : best[e];
                bw[e]   = lt ? p.x : bw[e];
            }
        }
        *(float4*)(out + base)     = make_float4(bw[0], bw[1], bw[2], bw[3]);
        *(float4*)(out + base + 4) = make_float4(bw[4], bw[5], bw[6], bw[7]);
    } else {
        for (long i = base; i < n; ++i) {
            float xv = x[i];
            float xx = xv * xv;
            asm volatile("" : "+v"(xx));
            float txv = xv + xv;
            float best = __builtin_inff(), bwv = 0.0f;
            for (int k = 0; k < kk; ++k) {
                float2 p = wp[k];
                float s    = xx + p.y;
                float prod = txv * p.x;
                asm volatile("" : "+v"(prod));
                float d = s - prod;
                if (d < best) { best = d; bwv = p.x; }
            }
            out[i] = bwv;
        }
    }
}

extern "C" void kernel_launch(void* const* d_in, const int* in_sizes, int n_in,
                              void* d_out, int out_size, void* d_ws, size_t ws_size,
                              hipStream_t stream) {
    const float* x = (const float*)d_in[0];
    const float* w = (const float*)d_in[1];
    float* out     = (float*)d_out;
    long n = (long)in_sizes[0];
    int  kk = in_sizes[1] < K ? in_sizes[1] : K;

    long threads_needed = (n + EPT - 1) / EPT;
    long grid = (threads_needed + BLOCK - 1) / BLOCK;
    vq_kernel<<<(int)grid, BLOCK, 0, stream>>>(x, w, out, n, kk);
}

// Round 4
// 81.273 us; speedup vs baseline: 1.5943x; 1.5943x over previous
//
#include <hip/hip_runtime.h>

// Quantizer_189: 1-D VQ codebook lookup. x: [16,1,512,512] fp32 (N=4,194,304
// scalars; C=D=1 so transposes are no-ops), weight: [128,1].
//
// Reference model (NumPy fp32, per-op rounding, NO fma — verified round 3,
// absmax == 0.0):
//   dist_k = fl( fl( fl(x*x) + fl(w_k*w_k) ) - fl( fl(2x) * w_k ) )
//   idx    = np.argmin(dist) — first ORIGINAL index wins ties
//   out    = w[idx]
//
// Round-4 algorithm: sort codebook per block, binary-search insertion point,
// evaluate the EXACT reference fp32 distance on the 8 sorted candidates
// [pos-4, pos+3]. Rounding noise in the expansion is <= ~7e-7*x^2, so a
// non-window entry can win only if >=4 codebook entries pack within ~4e-3 —
// negligible for 128 N(0,1) draws. Ties in the fp32 dist are broken by
// original index via a rare predicated branch (matches np.argmin).
//
// CRITICAL (round 1/2 lesson): device default -ffp-contract fuses mul into
// sub -> fma, breaking bit-exactness. Keep pragma + opaque asm barriers on
// every product.

constexpr int K     = 128;
constexpr int EPT   = 8;
constexpr int BLOCK = 256;

__global__ __launch_bounds__(BLOCK) void vq_kernel(const float* __restrict__ x,
                                                   const float* __restrict__ w,
                                                   float* __restrict__ out,
                                                   long n, int kk) {
#pragma clang fp contract(off)
    __shared__ float  wraw[K];  // original-order codebook
    __shared__ float  sv[K];    // sorted values (ascending, stable by orig idx)
    __shared__ float2 wp[K];    // (w, fl(w*w)) in sorted order
    __shared__ int    si[K];    // original index per sorted pos

    const int t = threadIdx.x;
    if (t < K) {
        wraw[t] = (t < kk) ? w[t] : __builtin_inff();
        sv[t]   = __builtin_inff();                       // pad slots
        wp[t]   = make_float2(__builtin_inff(), __builtin_inff());
        si[t]   = 0x7fffffff;
    }
    __syncthreads();
    if (t < kk) {
        // Stable O(K) rank sort per thread: rank = #{strictly less} + #{equal, earlier}.
        float v = wraw[t];
        int rank = 0;
        for (int j = 0; j < kk; ++j) {
            float u = wraw[j];
            rank += (u < v) || (u == v && j < t);
        }
        float v2 = v * v;                  // fl(w*w)
        asm volatile("" : "+v"(v2));       // keep it a standalone product
        sv[rank] = v;
        wp[rank] = make_float2(v, v2);
        si[rank] = t;
    }
    __syncthreads();

    // First 3 search levels from registers (block-uniform values).
    const float m1  = sv[63];
    const float m2a = sv[31],  m2b = sv[95];
    const float m3a = sv[15],  m3b = sv[47], m3c = sv[79], m3d = sv[111];

    long base = ((long)blockIdx.x * BLOCK + t) * (long)EPT;
    if (base + EPT <= n) {
        float4 a = *(const float4*)(x + base);
        float4 b = *(const float4*)(x + base + 4);
        float xs[EPT] = {a.x, a.y, a.z, a.w, b.x, b.y, b.z, b.w};
        float res[EPT];
#pragma unroll
        for (int e = 0; e < EPT; ++e) {
            float xv = xs[e];
            float x2 = xv * xv;            // fl(x*x)
            asm volatile("" : "+v"(x2));   // block fma(x,x,w2)
            float tx = xv + xv;            // fl(2x), exact

            // Branchless lower_bound: pos = #{sv < xv}. Levels 64/32/16 from
            // registers, 8/4/2/1 from LDS.
            int pos = (m1 < xv) ? 64 : 0;
            float m2 = (pos & 64) ? m2b : m2a;
            pos += (m2 < xv) ? 32 : 0;
            float m3lo = (pos & 32) ? m3b : m3a;
            float m3hi = (pos & 32) ? m3d : m3c;
            float m3   = (pos & 64) ? m3hi : m3lo;
            pos += (m3 < xv) ? 16 : 0;
#pragma unroll
            for (int step = 8; step > 0; step >>= 1)
                pos += (sv[pos + step - 1] < xv) ? step : 0;

            // Candidate window [pos-4, pos+3], clamped.
            int s = pos - 4;
            int smax = (kk > 8 ? kk : 8) - 8;
            s = s < 0 ? 0 : (s > smax ? smax : s);

            float best = __builtin_inff();
            int bestPos = s;
            float bw = 0.0f;
#pragma unroll
            for (int c = 0; c < 8; ++c) {
                float2 p = wp[s + c];
                float sum  = x2 + p.y;          // fl(x^2 + w^2)
                float prod = tx * p.x;          // fl(2x * w)
                asm volatile("" : "+v"(prod));  // block fma fusion into sub
                float d = sum - prod;           // fl(sum - prod)
                if (d < best) {
                    best = d; bestPos = s + c; bw = p.x;
                } else if (d == best) {
                    // Exact fp32-dist tie: np.argmin keeps smallest ORIGINAL index.
                    if (si[s + c] < si[bestPos]) { bestPos = s + c; bw = p.x; }
                }
            }
            res[e] = bw;
        }
        *(float4*)(out + base)     = make_float4(res[0], res[1], res[2], res[3]);
        *(float4*)(out + base + 4) = make_float4(res[4], res[5], res[6], res[7]);
    } else {
        // Tail (not hit for N=4,194,304): exact brute force over kk entries.
        for (long i = base; i < n; ++i) {
            float xv = x[i];
            float x2 = xv * xv;
            asm volatile("" : "+v"(x2));
            float tx = xv + xv;
            float best = __builtin_inff(), bwv = 0.0f;
            int bestIdx = 0x7fffffff;
            for (int p0 = 0; p0 < kk; ++p0) {
                float2 p = wp[p0];
                float sum  = x2 + p.y;
                float prod = tx * p.x;
                asm volatile("" : "+v"(prod));
                float d = sum - prod;
                if (d < best || (d == best && si[p0] < bestIdx)) {
                    best = d; bwv = p.x; bestIdx = si[p0];
                }
            }
            out[i] = bwv;
        }
    }
}

extern "C" void kernel_launch(void* const* d_in, const int* in_sizes, int n_in,
                              void* d_out, int out_size, void* d_ws, size_t ws_size,
                              hipStream_t stream) {
    const float* x = (const float*)d_in[0];
    const float* w = (const float*)d_in[1];
    float* out     = (float*)d_out;
    long n = (long)in_sizes[0];
    int  kk = in_sizes[1] < K ? in_sizes[1] : K;

    long threads_needed = (n + EPT - 1) / EPT;
    long grid = (threads_needed + BLOCK - 1) / BLOCK;
    vq_kernel<<<(int)grid, BLOCK, 0, stream>>>(x, w, out, n, kk);
}